// Round 7
// baseline (763.391 us; speedup 1.0000x reference)
//
#include <hip/hip_runtime.h>
#include <hip/hip_bf16.h>
#include <math.h>

// BiasFilter round 7: round-6 MFMA split GEMM + (T2) LDS chunk-rotation swizzle
// (bank conflicts 8-way -> 2-way) + (T1) bijective XCD swizzle (A-panel L2 reuse).
// Math bit-identical to round 6 (absmax must stay 2.4414e-4).

#define M_TOK (8 * 4096)   // 32768 tokens
#define E_DIM 1024
#define H_DIM 512
#define NBIAS 10
#define NXCD 8

typedef unsigned short ushort_t;
typedef unsigned int u32;
typedef __attribute__((ext_vector_type(8))) short bf16x8;
typedef __attribute__((ext_vector_type(4))) float f32x4;

__device__ __forceinline__ float gelu_erf(float t) {
    return 0.5f * t * (1.0f + erff(t * 0.70710678118654752440f));
}
__device__ __forceinline__ float bf2f(ushort_t h) {
    return __uint_as_float((u32)h << 16);
}
__device__ __forceinline__ ushort_t f2bf(float f) {   // RNE
    u32 u = __float_as_uint(f);
    u32 r = 0x7fffu + ((u >> 16) & 1u);
    return (ushort_t)((u + r) >> 16);
}

// ---------------- split conversion: src f32 -> hi/lo bf16 (RNE; lo exact residual)
__global__ __launch_bounds__(256) void conv_split_kernel(
    const float* __restrict__ src, ushort_t* __restrict__ hi,
    ushort_t* __restrict__ lo, int n4) {
    for (int i = blockIdx.x * 256 + threadIdx.x; i < n4; i += gridDim.x * 256) {
        float4 v = ((const float4*)src)[i];
        ushort4 h, l;
        h.x = f2bf(v.x); l.x = f2bf(v.x - bf2f(h.x));
        h.y = f2bf(v.y); l.y = f2bf(v.y - bf2f(h.y));
        h.z = f2bf(v.z); l.z = f2bf(v.z - bf2f(h.z));
        h.w = f2bf(v.w); l.w = f2bf(v.w - bf2f(h.w));
        ((ushort4*)hi)[i] = h;
        ((ushort4*)lo)[i] = l;
    }
}

// ---------------- split-bf16 MFMA GEMM: C = act(A @ B^T + bias)
// A[M,K], B[N,K] hi/lo bf16 pairs. BM=BN=128, BK=32, 256 thr = 4 waves,
// wave-tile 64x64 (4x4 frags of 16x16x32). acc += Ah*Bh + Ah*Bl + Al*Bh.
// T2: LDS slot (row r, 16B-pos p) holds global chunk c=(p-(r>>1))&3; LDS dest
// linear (global_load_lds requirement), source col pre-swizzled per-lane.
// T1: bijective XCD remap so each XCD owns a contiguous row-block chunk.
template <int SPLIT_OUT>
__global__ __launch_bounds__(256) void gemm_mfma_split(
    const ushort_t* __restrict__ Ahi, const ushort_t* __restrict__ Alo,
    const ushort_t* __restrict__ Bhi, const ushort_t* __restrict__ Blo,
    const float* __restrict__ bias,
    ushort_t* __restrict__ Chi, ushort_t* __restrict__ Clo,
    float* __restrict__ Cf, int N, int K) {
    __shared__ ushort_t lds[4][128 * 32];   // Ahi | Alo | Bhi | Blo tiles, [128 rows][32 k]

    const int tid = threadIdx.x;
    const int w = tid >> 6, lane = tid & 63;

    // ---- T1: bijective XCD swizzle (m204). dispatch slot -> XCD = slot % 8.
    const int nwg = gridDim.x * gridDim.y;
    const int lin = blockIdx.y * gridDim.x + blockIdx.x;
    const int q = nwg / NXCD, rr = nwg % NXCD;
    const int xcd = lin % NXCD, pos = lin / NXCD;
    const int newlin = (xcd < rr ? xcd * (q + 1) : rr * (q + 1) + (xcd - rr) * q) + pos;
    const int bm = (newlin / gridDim.x) * 128;
    const int bn = (newlin % gridDim.x) * 128;

    const int wr = w >> 1, wc = w & 1;

    // ---- staging: wave w stages matrix w. lane -> dest row (lane>>2) within each
    // 16-row segment, dest pos (lane&3). Source chunk c = ((lane&3) - (r>>1))&3,
    // and (r>>1)&3 == (lane>>3)&3 for every segment -> lane-static source col.
    const ushort_t* gsrc = (w == 0) ? Ahi : (w == 1) ? Alo : (w == 2) ? Bhi : Blo;
    const int grow0 = (w < 2) ? bm : bn;
    const int cswz = (((lane & 3) - ((lane >> 3) & 3)) & 3) * 8;   // elem col
    const ushort_t* gbase = gsrc + (size_t)(grow0 + (lane >> 2)) * K + cswz;

    f32x4 acc[4][4] = {};

    const int arow = wr * 64 + (lane & 15);
    const int brow = wc * 64 + (lane & 15);
    // read pos p = (chunk + (row>>1))&3; (row>>1)&3 == ((lane&15)>>1)&3 for all m.
    const int kgrp = ((((lane >> 4) + ((lane & 15) >> 1)) & 3)) * 8;

    for (int k0 = 0; k0 < K; k0 += 32) {
        __syncthreads();   // prior ds_reads done before overwrite
#pragma unroll
        for (int s = 0; s < 8; ++s) {
            __builtin_amdgcn_global_load_lds(
                (const __attribute__((address_space(1))) u32*)(const void*)(gbase + (size_t)(s * 16) * K + k0),
                (__attribute__((address_space(3))) u32*)(void*)(&lds[w][s * 16 * 32]),
                16, 0, 0);
        }
        __syncthreads();   // barrier drains vmcnt(0) -> tile visible

        bf16x8 a[2][4], b[2][4];
#pragma unroll
        for (int m = 0; m < 4; ++m) {
            a[0][m] = *(const bf16x8*)&lds[0][(arow + m * 16) * 32 + kgrp];
            a[1][m] = *(const bf16x8*)&lds[1][(arow + m * 16) * 32 + kgrp];
        }
#pragma unroll
        for (int n = 0; n < 4; ++n) {
            b[0][n] = *(const bf16x8*)&lds[2][(brow + n * 16) * 32 + kgrp];
            b[1][n] = *(const bf16x8*)&lds[3][(brow + n * 16) * 32 + kgrp];
        }
#pragma unroll
        for (int m = 0; m < 4; ++m)
#pragma unroll
            for (int n = 0; n < 4; ++n) {
                acc[m][n] = __builtin_amdgcn_mfma_f32_16x16x32_bf16(a[0][m], b[0][n], acc[m][n], 0, 0, 0);
                acc[m][n] = __builtin_amdgcn_mfma_f32_16x16x32_bf16(a[0][m], b[1][n], acc[m][n], 0, 0, 0);
                acc[m][n] = __builtin_amdgcn_mfma_f32_16x16x32_bf16(a[1][m], b[0][n], acc[m][n], 0, 0, 0);
            }
    }

    // epilogue: C/D layout col=lane&15, row=(lane>>4)*4+reg  [m89/m91-verified]
    const int crow0 = bm + wr * 64 + (lane >> 4) * 4;
    const int ccol0 = bn + wc * 64;
    const int csub = lane & 15;
#pragma unroll
    for (int m = 0; m < 4; ++m)
#pragma unroll
        for (int n = 0; n < 4; ++n) {
            const int col = ccol0 + n * 16 + csub;
            const float bv = bias[col];
#pragma unroll
            for (int r = 0; r < 4; ++r) {
                const size_t idx = (size_t)(crow0 + m * 16 + r) * N + col;
                const float v = acc[m][n][r] + bv;
                if (SPLIT_OUT) {
                    const ushort_t h = f2bf(v);
                    Chi[idx] = h;
                    Clo[idx] = f2bf(v - bf2f(h));
                } else {
                    Cf[idx] = gelu_erf(v);
                }
            }
        }
}

// ---------------- LayerNorm (two-pass var) + exact GELU on hi/lo bf16 rows, in place.
__global__ __launch_bounds__(256) void ln_gelu_split_kernel(
    ushort_t* __restrict__ hhi, ushort_t* __restrict__ hlo,
    const float* __restrict__ gamma, const float* __restrict__ beta) {
    __shared__ float sbuf[8];
    const int tid = threadIdx.x;
    const size_t base = (size_t)blockIdx.x * E_DIM + tid * 4;
    const ushort4 vh = *(const ushort4*)(hhi + base);
    const ushort4 vl = *(const ushort4*)(hlo + base);
    float f0 = bf2f(vh.x) + bf2f(vl.x);
    float f1 = bf2f(vh.y) + bf2f(vl.y);
    float f2 = bf2f(vh.z) + bf2f(vl.z);
    float f3 = bf2f(vh.w) + bf2f(vl.w);

    float s = f0 + f1 + f2 + f3;
#pragma unroll
    for (int off = 1; off < 64; off <<= 1) s += __shfl_xor(s, off);
    if ((tid & 63) == 0) sbuf[tid >> 6] = s;
    __syncthreads();
    const float mean = (sbuf[0] + sbuf[1] + sbuf[2] + sbuf[3]) * (1.0f / E_DIM);

    const float d0 = f0 - mean, d1 = f1 - mean, d2 = f2 - mean, d3 = f3 - mean;
    float s2 = d0 * d0 + d1 * d1 + d2 * d2 + d3 * d3;
#pragma unroll
    for (int off = 1; off < 64; off <<= 1) s2 += __shfl_xor(s2, off);
    if ((tid & 63) == 0) sbuf[4 + (tid >> 6)] = s2;
    __syncthreads();
    const float var = (sbuf[4] + sbuf[5] + sbuf[6] + sbuf[7]) * (1.0f / E_DIM);
    const float rstd = 1.0f / sqrtf(var + 1e-5f);

    const float4 gm = ((const float4*)gamma)[tid];
    const float4 bt = ((const float4*)beta)[tid];
    float o0 = gelu_erf(d0 * rstd * gm.x + bt.x);
    float o1 = gelu_erf(d1 * rstd * gm.y + bt.y);
    float o2 = gelu_erf(d2 * rstd * gm.z + bt.z);
    float o3 = gelu_erf(d3 * rstd * gm.w + bt.w);

    ushort4 oh, ol;
    oh.x = f2bf(o0); ol.x = f2bf(o0 - bf2f(oh.x));
    oh.y = f2bf(o1); ol.y = f2bf(o1 - bf2f(oh.y));
    oh.z = f2bf(o2); ol.z = f2bf(o2 - bf2f(oh.z));
    oh.w = f2bf(o3); ol.w = f2bf(o3 - bf2f(oh.w));
    *(ushort4*)(hhi + base) = oh;
    *(ushort4*)(hlo + base) = ol;
}

// ---------------- Scores + quaternion composition + rotation (fp32, unchanged).
__global__ __launch_bounds__(256) void score_rotate_kernel(
    const float* __restrict__ g, const float* __restrict__ W3,
    const float* __restrict__ b3, const float* __restrict__ quats,
    const float* __restrict__ thr_p, const float* __restrict__ x,
    float* __restrict__ out) {
    const int lane = threadIdx.x & 63;
    const int wid = threadIdx.x >> 6;
    const int token = blockIdx.x * 4 + wid;

    const float4* grow = (const float4*)(g + (size_t)token * H_DIM);
    const float4 g0 = grow[lane * 2 + 0];
    const float4 g1 = grow[lane * 2 + 1];

    float dots[NBIAS];
#pragma unroll
    for (int n = 0; n < NBIAS; ++n) {
        const float4* wr = (const float4*)(W3 + n * H_DIM);
        const float4 w0 = wr[lane * 2 + 0];
        const float4 w1 = wr[lane * 2 + 1];
        float d = g0.x * w0.x + g0.y * w0.y + g0.z * w0.z + g0.w * w0.w;
        d += g1.x * w1.x + g1.y * w1.y + g1.z * w1.z + g1.w * w1.w;
        dots[n] = d;
    }
#pragma unroll
    for (int off = 1; off < 64; off <<= 1)
#pragma unroll
        for (int n = 0; n < NBIAS; ++n) dots[n] += __shfl_xor(dots[n], off);

    const float thr = thr_p[0];
    float qw = 1.0f, qx = 0.0f, qy = 0.0f, qz = 0.0f;
#pragma unroll
    for (int n = 0; n < NBIAS; ++n) {
        const float z = dots[n] + b3[n];
        const float s = 1.0f / (1.0f + expf(-z));
        if (s > thr) {
            const float w1 = quats[n * 4 + 0], x1 = quats[n * 4 + 1];
            const float y1 = quats[n * 4 + 2], z1 = quats[n * 4 + 3];
            const float nw = w1 * qw - x1 * qx - y1 * qy - z1 * qz;
            const float nx = w1 * qx + x1 * qw + y1 * qz - z1 * qy;
            const float ny = w1 * qy - x1 * qz + y1 * qw + z1 * qx;
            const float nz = w1 * qz + x1 * qy - y1 * qx + z1 * qw;
            qw = nw; qx = nx; qy = ny; qz = nz;
        }
    }

    const float4* xr = (const float4*)(x + (size_t)token * E_DIM);
    float4* orow = (float4*)(out + (size_t)token * E_DIM);
#pragma unroll
    for (int j = 0; j < 4; ++j) {
        const float4 p = xr[lane * 4 + j];
        float4 r;
        r.x = qw * p.x - qx * p.y - qy * p.z - qz * p.w;
        r.y = qw * p.y + qx * p.x + qy * p.w - qz * p.z;
        r.z = qw * p.z - qx * p.w + qy * p.x + qz * p.y;
        r.w = qw * p.w + qx * p.z - qy * p.y + qz * p.x;
        orow[lane * 4 + j] = r;
    }
}

extern "C" void kernel_launch(void* const* d_in, const int* in_sizes, int n_in,
                              void* d_out, int out_size, void* d_ws, size_t ws_size,
                              hipStream_t stream) {
    const float* x     = (const float*)d_in[0];
    const float* W1    = (const float*)d_in[1];
    const float* b1    = (const float*)d_in[2];
    const float* ln_g  = (const float*)d_in[3];
    const float* ln_b  = (const float*)d_in[4];
    const float* W2    = (const float*)d_in[5];
    const float* b2    = (const float*)d_in[6];
    const float* W3    = (const float*)d_in[7];
    const float* b3    = (const float*)d_in[8];
    const float* quats = (const float*)d_in[9];
    const float* thr   = (const float*)d_in[10];
    float* out = (float*)d_out;

    // ---- workspace layout: W splits (fixed 6 MB) + chunk buffers
    char* p = (char*)d_ws;
    ushort_t* W1hi = (ushort_t*)p; p += (size_t)E_DIM * E_DIM * 2;
    ushort_t* W1lo = (ushort_t*)p; p += (size_t)E_DIM * E_DIM * 2;
    ushort_t* W2hi = (ushort_t*)p; p += (size_t)H_DIM * E_DIM * 2;
    ushort_t* W2lo = (ushort_t*)p; p += (size_t)H_DIM * E_DIM * 2;
    const size_t fixed = (size_t)(p - (char*)d_ws);

    // pick largest chunk Mc (tokens) fitting ws
    int Mc = M_TOK;
    while (Mc > 128) {
        const size_t need = fixed + (size_t)Mc * (E_DIM * 2 * 2 /*x*/ + E_DIM * 2 * 2 /*h*/ + H_DIM * 4 /*g*/);
        if (need <= ws_size) break;
        Mc >>= 1;
    }
    ushort_t* xhi = (ushort_t*)p; p += (size_t)Mc * E_DIM * 2;
    ushort_t* xlo = (ushort_t*)p; p += (size_t)Mc * E_DIM * 2;
    ushort_t* hhi = (ushort_t*)p; p += (size_t)Mc * E_DIM * 2;
    ushort_t* hlo = (ushort_t*)p; p += (size_t)Mc * E_DIM * 2;
    float*    gb  = (float*)p;

    dim3 blk(256);
    // weight splits (once per call)
    {
        int n4 = E_DIM * E_DIM / 4;
        conv_split_kernel<<<dim3(min(2048, (n4 + 255) / 256)), blk, 0, stream>>>(W1, W1hi, W1lo, n4);
        n4 = H_DIM * E_DIM / 4;
        conv_split_kernel<<<dim3(min(2048, (n4 + 255) / 256)), blk, 0, stream>>>(W2, W2hi, W2lo, n4);
    }

    for (int r0 = 0; r0 < M_TOK; r0 += Mc) {
        const float* xc = x + (size_t)r0 * E_DIM;
        // split x chunk
        const int n4 = Mc * E_DIM / 4;
        conv_split_kernel<<<dim3(min(2048, (n4 + 255) / 256)), blk, 0, stream>>>(xc, xhi, xlo, n4);
        // h(split) = x @ W1^T + b1
        gemm_mfma_split<1><<<dim3(E_DIM / 128, Mc / 128), blk, 0, stream>>>(
            xhi, xlo, W1hi, W1lo, b1, hhi, hlo, nullptr, E_DIM, E_DIM);
        // h = gelu(LN(h)) in place on the split pair
        ln_gelu_split_kernel<<<dim3(Mc), blk, 0, stream>>>(hhi, hlo, ln_g, ln_b);
        // g = gelu(h @ W2^T + b2), f32
        gemm_mfma_split<0><<<dim3(H_DIM / 128, Mc / 128), blk, 0, stream>>>(
            hhi, hlo, W2hi, W2lo, b2, nullptr, nullptr, gb, H_DIM, E_DIM);
        // scores -> mask -> compose -> rotate
        score_rotate_kernel<<<dim3(Mc / 4), blk, 0, stream>>>(
            gb, W3, b3, quats, thr, xc, out + (size_t)r0 * E_DIM);
    }
}

// Round 11
// 693.470 us; speedup vs baseline: 1.1008x; 1.1008x over previous
//
#include <hip/hip_runtime.h>
#include <hip/hip_bf16.h>
#include <math.h>

// BiasFilter round 8 source (4th submit; rounds 8-10 hit GPUAcquisitionTimeout):
// deep-pipelined split-bf16 MFMA GEMM (T3+T4+T2+T5).
// 256x256 tile, 512 thr (8 waves 2x4), BK=32, 4-deep LDS ring (128 KiB),
// stage-3-tiles-ahead with counted vmcnt(8) (never 0 in steady state),
// raw s_barrier (1 per K-tile). hi/lo split as virtual K=3072:
// seg0 (Ah,Bh), seg1 (Ah,Bl), seg2 (Al,Bh). Swizzles carried from round 7.

#define M_TOK (8 * 4096)   // 32768 tokens
#define E_DIM 1024
#define H_DIM 512
#define NBIAS 10
#define NXCD 8

typedef unsigned short ushort_t;
typedef unsigned int u32;
typedef __attribute__((ext_vector_type(8))) short bf16x8;
typedef __attribute__((ext_vector_type(4))) float f32x4;

__device__ __forceinline__ float gelu_erf(float t) {
    return 0.5f * t * (1.0f + erff(t * 0.70710678118654752440f));
}
__device__ __forceinline__ float bf2f(ushort_t h) {
    return __uint_as_float((u32)h << 16);
}
__device__ __forceinline__ ushort_t f2bf(float f) {   // RNE
    u32 u = __float_as_uint(f);
    u32 r = 0x7fffu + ((u >> 16) & 1u);
    return (ushort_t)((u + r) >> 16);
}

// ---------------- split conversion: src f32 -> hi/lo bf16
__global__ __launch_bounds__(256) void conv_split_kernel(
    const float* __restrict__ src, ushort_t* __restrict__ hi,
    ushort_t* __restrict__ lo, int n4) {
    for (int i = blockIdx.x * 256 + threadIdx.x; i < n4; i += gridDim.x * 256) {
        float4 v = ((const float4*)src)[i];
        ushort4 h, l;
        h.x = f2bf(v.x); l.x = f2bf(v.x - bf2f(h.x));
        h.y = f2bf(v.y); l.y = f2bf(v.y - bf2f(h.y));
        h.z = f2bf(v.z); l.z = f2bf(v.z - bf2f(h.z));
        h.w = f2bf(v.w); l.w = f2bf(v.w - bf2f(h.w));
        ((ushort4*)hi)[i] = h;
        ((ushort4*)lo)[i] = l;
    }
}

// ---------------- deep-pipelined split GEMM: C = act(A @ B^T + bias)
// A[M,1024], B[N,1024] hi/lo bf16. Virtual K = 3072, NT = 96 BK=32 tiles.
// LDS ring: buf[t&3] = {A 256x32 | B 256x32}. Stage tile t+3 during tile t.
// vmcnt ledger: 4 gloads/thread/tile; at end of tile t wait so that loads
// for tile t+1 (issued during t-2) are complete: allow 8 outstanding
// (tiles t+2,t+3), 4 near tail, 0 at tail. FIFO vmcnt semantics (m135).
template <int SPLIT_OUT>
__global__ __launch_bounds__(512, 2) void gemm8p(
    const ushort_t* __restrict__ Ahi, const ushort_t* __restrict__ Alo,
    const ushort_t* __restrict__ Bhi, const ushort_t* __restrict__ Blo,
    const float* __restrict__ bias,
    ushort_t* __restrict__ Chi, ushort_t* __restrict__ Clo,
    float* __restrict__ Cf, int N) {
    constexpr int K = 1024;
    constexpr int NT = 96;            // 3 segments x 32 tiles
    __shared__ ushort_t lds[65536];   // 4 bufs x {A,B} x 256x32 = 128 KiB

    const int tid = threadIdx.x;
    const int w = tid >> 6, lane = tid & 63;
    const int wm = w >> 2, wn = w & 3;

    // T1: bijective XCD swizzle (m204)
    const int nwg = gridDim.x * gridDim.y;
    const int lin = blockIdx.y * gridDim.x + blockIdx.x;
    const int q = nwg / NXCD, rr = nwg % NXCD;
    const int xcd = lin % NXCD, pos = lin / NXCD;
    const int newlin = (xcd < rr ? xcd * (q + 1) : rr * (q + 1) + (xcd - rr) * q) + pos;
    const int bm = (newlin / gridDim.x) * 256;
    const int bn = (newlin % gridDim.x) * 256;

    // staging lane geometry (T2 chunk-rotation, verified r7): dest row
    // r = j*128 + w*16 + (lane>>2), dest pos = lane&3, source chunk
    // c = ((lane&3) - ((lane>>3)&3))&3  (since (r>>1)&3 == (lane>>3)&3).
    const int cswz = (((lane & 3) - ((lane >> 3) & 3)) & 3) * 8;
    const size_t aoff0 = (size_t)(bm + w * 16 + (lane >> 2)) * K + cswz;
    const size_t aoff1 = (size_t)(bm + 128 + w * 16 + (lane >> 2)) * K + cswz;
    const size_t boff0 = (size_t)(bn + w * 16 + (lane >> 2)) * K + cswz;
    const size_t boff1 = (size_t)(bn + 128 + w * 16 + (lane >> 2)) * K + cswz;
    const u32 ldw = w * 512;          // wave's dest elem base within a half

    // read-side geometry: pos p = ((k_chunk) + ((row>>1)&3))&3, row>>1&3
    // reduces to ((lane&15)>>1)&3 for all frag offsets (multiples of 8 rows).
    const int pr = (((lane >> 4) + (((lane & 15) >> 1) & 3)) & 3) * 8;
    const u32 arow_base = (u32)((wm * 128 + (lane & 15)) * 32) + pr;
    const u32 brow_base = (u32)((wn * 64 + (lane & 15)) * 32) + pr;

    f32x4 acc[8][4] = {};

#define STAGE_A(pt) do { \
    const int sg_ = (pt) >> 5; \
    const size_t kk_ = (size_t)(((pt) & 31) * 32); \
    const ushort_t* As_ = (sg_ == 2) ? Alo : Ahi; \
    const u32 db_ = ((u32)((pt) & 3)) * 16384 + ldw; \
    __builtin_amdgcn_global_load_lds( \
        (const __attribute__((address_space(1))) u32*)(const void*)(As_ + aoff0 + kk_), \
        (__attribute__((address_space(3))) u32*)(void*)(&lds[db_]), 16, 0, 0); \
    __builtin_amdgcn_global_load_lds( \
        (const __attribute__((address_space(1))) u32*)(const void*)(As_ + aoff1 + kk_), \
        (__attribute__((address_space(3))) u32*)(void*)(&lds[db_ + 4096]), 16, 0, 0); \
} while (0)

#define STAGE_B(pt) do { \
    const int sg_ = (pt) >> 5; \
    const size_t kk_ = (size_t)(((pt) & 31) * 32); \
    const ushort_t* Bs_ = (sg_ == 1) ? Blo : Bhi; \
    const u32 db_ = ((u32)((pt) & 3)) * 16384 + 8192 + ldw; \
    __builtin_amdgcn_global_load_lds( \
        (const __attribute__((address_space(1))) u32*)(const void*)(Bs_ + boff0 + kk_), \
        (__attribute__((address_space(3))) u32*)(void*)(&lds[db_]), 16, 0, 0); \
    __builtin_amdgcn_global_load_lds( \
        (const __attribute__((address_space(1))) u32*)(const void*)(Bs_ + boff1 + kk_), \
        (__attribute__((address_space(3))) u32*)(void*)(&lds[db_ + 4096]), 16, 0, 0); \
} while (0)

    // prologue: stage tiles 0,1,2 (12 gloads); wait tile-0 (allow 8), barrier.
    STAGE_A(0); STAGE_B(0);
    STAGE_A(1); STAGE_B(1);
    STAGE_A(2); STAGE_B(2);
    asm volatile("s_waitcnt vmcnt(8)" ::: "memory");
    __builtin_amdgcn_s_barrier();
    asm volatile("" ::: "memory");

    for (int t = 0; t < NT; ++t) {
        const u32 ab = ((u32)(t & 3)) * 16384;
        const u32 bb = ab + 8192;
        bf16x8 bf[4], af[4];
        // ---- phase 0: B-frags + A-frags m0-3, stage A(t+3), MFMA m0-3
#pragma unroll
        for (int n = 0; n < 4; ++n) bf[n] = *(const bf16x8*)&lds[bb + brow_base + n * 512];
#pragma unroll
        for (int m = 0; m < 4; ++m) af[m] = *(const bf16x8*)&lds[ab + arow_base + m * 512];
        if (t + 3 < NT) STAGE_A(t + 3);
        __builtin_amdgcn_s_setprio(1);
#pragma unroll
        for (int m = 0; m < 4; ++m)
#pragma unroll
            for (int n = 0; n < 4; ++n)
                acc[m][n] = __builtin_amdgcn_mfma_f32_16x16x32_bf16(af[m], bf[n], acc[m][n], 0, 0, 0);
        __builtin_amdgcn_s_setprio(0);
        // ---- phase 1: A-frags m4-7, stage B(t+3), MFMA m4-7
#pragma unroll
        for (int m = 0; m < 4; ++m) af[m] = *(const bf16x8*)&lds[ab + arow_base + (m + 4) * 512];
        if (t + 3 < NT) STAGE_B(t + 3);
        __builtin_amdgcn_s_setprio(1);
#pragma unroll
        for (int m = 0; m < 4; ++m)
#pragma unroll
            for (int n = 0; n < 4; ++n)
                acc[m + 4][n] = __builtin_amdgcn_mfma_f32_16x16x32_bf16(af[m], bf[n], acc[m + 4][n], 0, 0, 0);
        __builtin_amdgcn_s_setprio(0);
        // ---- tile boundary: counted vmcnt (tile t+1's loads complete), barrier
        if (t + 3 < NT)      asm volatile("s_waitcnt vmcnt(8)" ::: "memory");
        else if (t + 2 < NT) asm volatile("s_waitcnt vmcnt(4)" ::: "memory");
        else                 asm volatile("s_waitcnt vmcnt(0)" ::: "memory");
        __builtin_amdgcn_s_barrier();
        asm volatile("" ::: "memory");
    }
#undef STAGE_A
#undef STAGE_B

    // epilogue: C/D layout col=lane&15, row=(lane>>4)*4+reg
    const int crow0 = bm + wm * 128 + (lane >> 4) * 4;
    const int ccol0 = bn + wn * 64;
    const int csub = lane & 15;
#pragma unroll
    for (int m = 0; m < 8; ++m)
#pragma unroll
        for (int n = 0; n < 4; ++n) {
            const int col = ccol0 + n * 16 + csub;
            const float bv = bias[col];
#pragma unroll
            for (int r = 0; r < 4; ++r) {
                const size_t idx = (size_t)(crow0 + m * 16 + r) * N + col;
                const float v = acc[m][n][r] + bv;
                if (SPLIT_OUT) {
                    const ushort_t h = f2bf(v);
                    Chi[idx] = h;
                    Clo[idx] = f2bf(v - bf2f(h));
                } else {
                    Cf[idx] = gelu_erf(v);
                }
            }
        }
}

// ---------------- LayerNorm (two-pass var) + exact GELU on hi/lo bf16 rows, in place.
__global__ __launch_bounds__(256) void ln_gelu_split_kernel(
    ushort_t* __restrict__ hhi, ushort_t* __restrict__ hlo,
    const float* __restrict__ gamma, const float* __restrict__ beta) {
    __shared__ float sbuf[8];
    const int tid = threadIdx.x;
    const size_t base = (size_t)blockIdx.x * E_DIM + tid * 4;
    const ushort4 vh = *(const ushort4*)(hhi + base);
    const ushort4 vl = *(const ushort4*)(hlo + base);
    float f0 = bf2f(vh.x) + bf2f(vl.x);
    float f1 = bf2f(vh.y) + bf2f(vl.y);
    float f2 = bf2f(vh.z) + bf2f(vl.z);
    float f3 = bf2f(vh.w) + bf2f(vl.w);

    float s = f0 + f1 + f2 + f3;
#pragma unroll
    for (int off = 1; off < 64; off <<= 1) s += __shfl_xor(s, off);
    if ((tid & 63) == 0) sbuf[tid >> 6] = s;
    __syncthreads();
    const float mean = (sbuf[0] + sbuf[1] + sbuf[2] + sbuf[3]) * (1.0f / E_DIM);

    const float d0 = f0 - mean, d1 = f1 - mean, d2 = f2 - mean, d3 = f3 - mean;
    float s2 = d0 * d0 + d1 * d1 + d2 * d2 + d3 * d3;
#pragma unroll
    for (int off = 1; off < 64; off <<= 1) s2 += __shfl_xor(s2, off);
    if ((tid & 63) == 0) sbuf[4 + (tid >> 6)] = s2;
    __syncthreads();
    const float var = (sbuf[4] + sbuf[5] + sbuf[6] + sbuf[7]) * (1.0f / E_DIM);
    const float rstd = 1.0f / sqrtf(var + 1e-5f);

    const float4 gm = ((const float4*)gamma)[tid];
    const float4 bt = ((const float4*)beta)[tid];
    float o0 = gelu_erf(d0 * rstd * gm.x + bt.x);
    float o1 = gelu_erf(d1 * rstd * gm.y + bt.y);
    float o2 = gelu_erf(d2 * rstd * gm.z + bt.z);
    float o3 = gelu_erf(d3 * rstd * gm.w + bt.w);

    ushort4 oh, ol;
    oh.x = f2bf(o0); ol.x = f2bf(o0 - bf2f(oh.x));
    oh.y = f2bf(o1); ol.y = f2bf(o1 - bf2f(oh.y));
    oh.z = f2bf(o2); ol.z = f2bf(o2 - bf2f(oh.z));
    oh.w = f2bf(o3); ol.w = f2bf(o3 - bf2f(oh.w));
    *(ushort4*)(hhi + base) = oh;
    *(ushort4*)(hlo + base) = ol;
}

// ---------------- Scores + quaternion composition + rotation (fp32, unchanged).
__global__ __launch_bounds__(256) void score_rotate_kernel(
    const float* __restrict__ g, const float* __restrict__ W3,
    const float* __restrict__ b3, const float* __restrict__ quats,
    const float* __restrict__ thr_p, const float* __restrict__ x,
    float* __restrict__ out) {
    const int lane = threadIdx.x & 63;
    const int wid = threadIdx.x >> 6;
    const int token = blockIdx.x * 4 + wid;

    const float4* grow = (const float4*)(g + (size_t)token * H_DIM);
    const float4 g0 = grow[lane * 2 + 0];
    const float4 g1 = grow[lane * 2 + 1];

    float dots[NBIAS];
#pragma unroll
    for (int n = 0; n < NBIAS; ++n) {
        const float4* wr = (const float4*)(W3 + n * H_DIM);
        const float4 w0 = wr[lane * 2 + 0];
        const float4 w1 = wr[lane * 2 + 1];
        float d = g0.x * w0.x + g0.y * w0.y + g0.z * w0.z + g0.w * w0.w;
        d += g1.x * w1.x + g1.y * w1.y + g1.z * w1.z + g1.w * w1.w;
        dots[n] = d;
    }
#pragma unroll
    for (int off = 1; off < 64; off <<= 1)
#pragma unroll
        for (int n = 0; n < NBIAS; ++n) dots[n] += __shfl_xor(dots[n], off);

    const float thr = thr_p[0];
    float qw = 1.0f, qx = 0.0f, qy = 0.0f, qz = 0.0f;
#pragma unroll
    for (int n = 0; n < NBIAS; ++n) {
        const float z = dots[n] + b3[n];
        const float s = 1.0f / (1.0f + expf(-z));
        if (s > thr) {
            const float w1 = quats[n * 4 + 0], x1 = quats[n * 4 + 1];
            const float y1 = quats[n * 4 + 2], z1 = quats[n * 4 + 3];
            const float nw = w1 * qw - x1 * qx - y1 * qy - z1 * qz;
            const float nx = w1 * qx + x1 * qw + y1 * qz - z1 * qy;
            const float ny = w1 * qy - x1 * qz + y1 * qw + z1 * qx;
            const float nz = w1 * qz + x1 * qy - y1 * qx + z1 * qw;
            qw = nw; qx = nx; qy = ny; qz = nz;
        }
    }

    const float4* xr = (const float4*)(x + (size_t)token * E_DIM);
    float4* orow = (float4*)(out + (size_t)token * E_DIM);
#pragma unroll
    for (int j = 0; j < 4; ++j) {
        const float4 p = xr[lane * 4 + j];
        float4 r;
        r.x = qw * p.x - qx * p.y - qy * p.z - qz * p.w;
        r.y = qw * p.y + qx * p.x + qy * p.w - qz * p.z;
        r.z = qw * p.z - qx * p.w + qy * p.x + qz * p.y;
        r.w = qw * p.w + qx * p.z - qy * p.y + qz * p.x;
        orow[lane * 4 + j] = r;
    }
}

extern "C" void kernel_launch(void* const* d_in, const int* in_sizes, int n_in,
                              void* d_out, int out_size, void* d_ws, size_t ws_size,
                              hipStream_t stream) {
    const float* x     = (const float*)d_in[0];
    const float* W1    = (const float*)d_in[1];
    const float* b1    = (const float*)d_in[2];
    const float* ln_g  = (const float*)d_in[3];
    const float* ln_b  = (const float*)d_in[4];
    const float* W2    = (const float*)d_in[5];
    const float* b2    = (const float*)d_in[6];
    const float* W3    = (const float*)d_in[7];
    const float* b3    = (const float*)d_in[8];
    const float* quats = (const float*)d_in[9];
    const float* thr   = (const float*)d_in[10];
    float* out = (float*)d_out;

    // ---- workspace layout: W splits (fixed 6 MB) + chunk buffers
    char* p = (char*)d_ws;
    ushort_t* W1hi = (ushort_t*)p; p += (size_t)E_DIM * E_DIM * 2;
    ushort_t* W1lo = (ushort_t*)p; p += (size_t)E_DIM * E_DIM * 2;
    ushort_t* W2hi = (ushort_t*)p; p += (size_t)H_DIM * E_DIM * 2;
    ushort_t* W2lo = (ushort_t*)p; p += (size_t)H_DIM * E_DIM * 2;
    const size_t fixed = (size_t)(p - (char*)d_ws);

    // largest chunk Mc (multiple of 256) fitting ws
    int Mc = M_TOK;
    while (Mc > 256) {
        const size_t need = fixed + (size_t)Mc * (E_DIM * 2 * 2 /*x*/ + E_DIM * 2 * 2 /*h*/ + H_DIM * 4 /*g*/);
        if (need <= ws_size) break;
        Mc >>= 1;
    }
    ushort_t* xhi = (ushort_t*)p; p += (size_t)Mc * E_DIM * 2;
    ushort_t* xlo = (ushort_t*)p; p += (size_t)Mc * E_DIM * 2;
    ushort_t* hhi = (ushort_t*)p; p += (size_t)Mc * E_DIM * 2;
    ushort_t* hlo = (ushort_t*)p; p += (size_t)Mc * E_DIM * 2;
    float*    gb  = (float*)p;

    dim3 blk(256);
    // weight splits (once per call)
    {
        int n4 = E_DIM * E_DIM / 4;
        conv_split_kernel<<<dim3(min(2048, (n4 + 255) / 256)), blk, 0, stream>>>(W1, W1hi, W1lo, n4);
        n4 = H_DIM * E_DIM / 4;
        conv_split_kernel<<<dim3(min(2048, (n4 + 255) / 256)), blk, 0, stream>>>(W2, W2hi, W2lo, n4);
    }

    for (int r0 = 0; r0 < M_TOK; r0 += Mc) {
        const float* xc = x + (size_t)r0 * E_DIM;
        const int n4 = Mc * E_DIM / 4;
        conv_split_kernel<<<dim3(min(2048, (n4 + 255) / 256)), blk, 0, stream>>>(xc, xhi, xlo, n4);
        // h(split) = x @ W1^T + b1
        gemm8p<1><<<dim3(E_DIM / 256, Mc / 256), dim3(512), 0, stream>>>(
            xhi, xlo, W1hi, W1lo, b1, hhi, hlo, nullptr, E_DIM);
        // h = gelu(LN(h)) in place
        ln_gelu_split_kernel<<<dim3(Mc), blk, 0, stream>>>(hhi, hlo, ln_g, ln_b);
        // g = gelu(h @ W2^T + b2), f32
        gemm8p<0><<<dim3(H_DIM / 256, Mc / 256), dim3(512), 0, stream>>>(
            hhi, hlo, W2hi, W2lo, b2, nullptr, nullptr, gb, H_DIM);
        // scores -> mask -> compose -> rotate
        score_rotate_kernel<<<dim3(Mc / 4), blk, 0, stream>>>(
            gb, W3, b3, quats, thr, xc, out + (size_t)r0 * E_DIM);
    }
}